// Round 3
// baseline (623.508 us; speedup 1.0000x reference)
//
#include <hip/hip_runtime.h>
#include <hip/hip_bf16.h>

// ---------------------------------------------------------------------------
// Axis_Portrait_Attention: B=4, C=Cr=256, H=W=128, HW=16384
// outputs (fp32, concat): out_w[4,256,128,128], x_Qw[4,128,32768],
//                         x_Kw[4,32768,128],  x_Vw[4,32768,128],
//                         gamma[1], attn[4,128,128]
// Round 3: byte-diet. K2f eliminated (k_qk stages K from x_Kw via LDS).
// k_qkv = 2x32-pos subtiles per block (256B write chunks). k_up 2x64-pos
// subtiles + nontemporal outw. k_qk: 128 j-splits, LDS-staged pre-split K.
// ---------------------------------------------------------------------------

typedef __attribute__((ext_vector_type(8))) short bf16x8;   // 8 bf16 (4 VGPR)
typedef __attribute__((ext_vector_type(4))) float f4;       // MFMA C/D

#define MFMA16(a, b, c) __builtin_amdgcn_mfma_f32_16x16x32_bf16(a, b, c, 0, 0, 0)

__device__ __forceinline__ unsigned short f2bf(float f) {  // RNE
  union { float f; unsigned u; } v; v.f = f;
  unsigned r = v.u + 0x7fffu + ((v.u >> 16) & 1u);
  return (unsigned short)(r >> 16);
}
__device__ __forceinline__ float bf2f(unsigned short h) {
  union { unsigned u; float f; } v; v.u = ((unsigned)h) << 16;
  return v.f;
}
__device__ __forceinline__ void splitf(float f, unsigned short &hi, unsigned short &lo) {
  unsigned short h = f2bf(f);
  hi = h; lo = f2bf(f - bf2f(h));
}

// truncation split of 8 floats -> hi/lo bf16x8 using v_perm packing (cheap).
__device__ __forceinline__ void split8t(float4 a, float4 b, bf16x8 &hi, bf16x8 &lo) {
  union { bf16x8 v; unsigned u[4]; } uh, ul;
  const unsigned* ua = (const unsigned*)&a;
  const unsigned* ub = (const unsigned*)&b;
  const float* fa = (const float*)&a;
  const float* fb = (const float*)&b;
#pragma unroll
  for (int e = 0; e < 2; ++e) {
    uh.u[e]     = __builtin_amdgcn_perm(ua[2*e+1], ua[2*e], 0x07060302u);
    uh.u[2 + e] = __builtin_amdgcn_perm(ub[2*e+1], ub[2*e], 0x07060302u);
    union { float f; unsigned u; } p0, p1, q0, q1;
    p0.u = ua[2*e] & 0xffff0000u;   p1.u = ua[2*e+1] & 0xffff0000u;
    p0.f = fa[2*e] - p0.f;          p1.f = fa[2*e+1] - p1.f;
    ul.u[e] = __builtin_amdgcn_perm(p1.u, p0.u, 0x07060302u);
    q0.u = ub[2*e] & 0xffff0000u;   q1.u = ub[2*e+1] & 0xffff0000u;
    q0.f = fb[2*e] - q0.f;          q1.f = fb[2*e+1] - q1.f;
    ul.u[2 + e] = __builtin_amdgcn_perm(q1.u, q0.u, 0x07060302u);
  }
  hi = uh.v; lo = ul.v;
}

// truncation-pack 8 floats -> bf16x8 (4 v_perm)
__device__ __forceinline__ bf16x8 pack8t(float4 a, float4 b) {
  union { bf16x8 v; unsigned u[4]; } r;
  const unsigned* ua = (const unsigned*)&a;
  const unsigned* ub = (const unsigned*)&b;
  r.u[0] = __builtin_amdgcn_perm(ua[1], ua[0], 0x07060302u);
  r.u[1] = __builtin_amdgcn_perm(ua[3], ua[2], 0x07060302u);
  r.u[2] = __builtin_amdgcn_perm(ub[1], ub[0], 0x07060302u);
  r.u[3] = __builtin_amdgcn_perm(ub[3], ub[2], 0x07060302u);
  return r.v;
}

// ---------------------------------------------------------------------------
// K0: precompute weight splits
// ---------------------------------------------------------------------------
__global__ __launch_bounds__(256) void k_prep(
    const float* __restrict__ Wq, const float* __restrict__ Wk,
    const float* __restrict__ Wv, const float* __restrict__ Wu,
    unsigned short* __restrict__ wqh, unsigned short* __restrict__ wql,
    unsigned short* __restrict__ wkh, unsigned short* __restrict__ wkl,
    unsigned short* __restrict__ wvh, unsigned short* __restrict__ wuh) {
  const int i = blockIdx.x * 256 + threadIdx.x;  // 65536 total
  unsigned short h, lo2;
  splitf(Wq[i], h, lo2); wqh[i] = h; wql[i] = lo2;
  splitf(Wk[i], h, lo2); wkh[i] = h; wkl[i] = lo2;
  wvh[i] = f2bf(Wv[i]);
  wuh[i] = f2bf(Wu[i]);
}

// ---------------------------------------------------------------------------
// K1: fused QKV 1x1 conv.  Block: 256 out-channels x 64 positions as
// 2 subtiles of 32.  LDS 33.8KB (tbuf aliases xtlo) -> 4 blocks/CU.
// No K2f side-copy (k_qk reads x_Kw instead).
// ---------------------------------------------------------------------------
__global__ __launch_bounds__(256, 4) void k_qkv(
    const float* __restrict__ x,
    const unsigned short* __restrict__ wqh, const unsigned short* __restrict__ wql,
    const unsigned short* __restrict__ wkh, const unsigned short* __restrict__ wkl,
    const unsigned short* __restrict__ wvh,
    const float* __restrict__ bq, const float* __restrict__ bk,
    const float* __restrict__ bv,
    float* __restrict__ outQ, float* __restrict__ outKT, float* __restrict__ outVT) {
  const int pbv = blockIdx.x, b = blockIdx.y;
  const int t = threadIdx.x;

  __shared__ __align__(16) unsigned short xthi[32][264];
  __shared__ __align__(16) unsigned short xtlo[32][264];  // aliased by tbuf
  float (*tbuf)[132] = reinterpret_cast<float (*)[132]>(&xtlo[0][0]);

  const int wv = t >> 6, l = t & 63;
  const int lr = l & 15, lkq = l >> 4, lk = lkq * 8;
  const size_t ob = (size_t)b * 4194304;
  const f4 fz = {0.f, 0.f, 0.f, 0.f};
  f4 acc[4][2];

#pragma unroll 1
  for (int st = 0; st < 2; ++st) {
    const int p0 = pbv * 64 + st * 32;
    __syncthreads();  // protect LDS from previous subtile readers

    {  // stage x[b, :, p0..p0+31] transposed + split
      const int cp = t & 127;          // channel pair 2cp, 2cp+1
      const int hh = (t >> 7) * 16;    // position offset 0 / 16
      const float* r0 = x + ((size_t)b * 256 + 2 * cp) * 16384 + p0 + hh;
      const float* r1 = r0 + 16384;
#pragma unroll
      for (int q = 0; q < 4; ++q) {
        float4 v0 = *(const float4*)(r0 + 4 * q);
        float4 v1 = *(const float4*)(r1 + 4 * q);
        const unsigned* u0 = (const unsigned*)&v0;
        const unsigned* u1 = (const unsigned*)&v1;
        const float* f0 = (const float*)&v0;
        const float* f1 = (const float*)&v1;
#pragma unroll
        for (int e = 0; e < 4; ++e) {
          const int p = hh + 4 * q + e;
          *(unsigned*)&xthi[p][2 * cp] = __builtin_amdgcn_perm(u1[e], u0[e], 0x07060302u);
          union { float f; unsigned u; } l0, l1;
          l0.u = u0[e] & 0xffff0000u;  l1.u = u1[e] & 0xffff0000u;
          l0.f = f0[e] - l0.f;         l1.f = f1[e] - l1.f;
          *(unsigned*)&xtlo[p][2 * cp] = __builtin_amdgcn_perm(l1.u, l0.u, 0x07060302u);
        }
      }
    }
    __syncthreads();

#define CONV_PASS(WHI, WLO, SPLIT)                                        \
  {                                                                       \
    _Pragma("unroll") for (int mt = 0; mt < 4; ++mt)                      \
    _Pragma("unroll") for (int nt = 0; nt < 2; ++nt) acc[mt][nt] = fz;    \
    _Pragma("unroll 1") for (int kk = 0; kk < 8; ++kk) {                  \
      const int c0 = kk * 32 + lk;                                        \
      bf16x8 ahi[4], alo[4], bhi[2], blo[2];                              \
      _Pragma("unroll") for (int mt = 0; mt < 4; ++mt) {                  \
        const int o = wv * 64 + mt * 16 + lr;                             \
        ahi[mt] = *(const bf16x8*)(WHI + o * 256 + c0);                   \
        if (SPLIT) alo[mt] = *(const bf16x8*)(WLO + o * 256 + c0);        \
      }                                                                   \
      _Pragma("unroll") for (int nt = 0; nt < 2; ++nt) {                  \
        bhi[nt] = *(const bf16x8*)&xthi[nt * 16 + lr][c0];                \
        if (SPLIT) blo[nt] = *(const bf16x8*)&xtlo[nt * 16 + lr][c0];     \
      }                                                                   \
      _Pragma("unroll") for (int mt = 0; mt < 4; ++mt)                    \
      _Pragma("unroll") for (int nt = 0; nt < 2; ++nt) {                  \
        acc[mt][nt] = MFMA16(ahi[mt], bhi[nt], acc[mt][nt]);              \
        if (SPLIT) {                                                      \
          acc[mt][nt] = MFMA16(ahi[mt], blo[nt], acc[mt][nt]);            \
          acc[mt][nt] = MFMA16(alo[mt], bhi[nt], acc[mt][nt]);            \
        }                                                                 \
      }                                                                   \
    }                                                                     \
  }

#define TRANSPOSE_OUT(DST)                                                   \
  _Pragma("unroll") for (int par = 0; par < 2; ++par) {                      \
    __syncthreads();                                                         \
    _Pragma("unroll") for (int mt = 0; mt < 4; ++mt)                         \
    _Pragma("unroll") for (int m = 0; m < 2; ++m) {                          \
      const int i = wv * 32 + mt * 8 + lkq * 2 + m;                          \
      const int e = par + 2 * m;                                             \
      _Pragma("unroll") for (int nt = 0; nt < 2; ++nt)                       \
        tbuf[nt * 16 + lr][i] = acc[mt][nt][e];                              \
    }                                                                        \
    __syncthreads();                                                         \
    {                                                                        \
      const int pr = t >> 3, c4 = (t & 7) * 16;                              \
      float* dst = DST + ob + (size_t)(par * 16384 + p0 + pr) * 128 + c4;    \
      _Pragma("unroll") for (int q2 = 0; q2 < 4; ++q2)                       \
        *(float4*)(dst + 4 * q2) = *(const float4*)&tbuf[pr][c4 + 4 * q2];   \
    }                                                                        \
  }

    // ---------------- Q (split precision, contiguous out) ----------------
    CONV_PASS(wqh, wql, 1)
    {
      const int rbase = wv * 64 + lkq * 4;
#pragma unroll
      for (int mt = 0; mt < 4; ++mt)
#pragma unroll
        for (int e = 0; e < 4; ++e) {
          const int o = rbase + mt * 16 + e;
          const float bb = bq[o];
#pragma unroll
          for (int nt = 0; nt < 2; ++nt)
            outQ[ob + (size_t)o * 16384 + (p0 + nt * 16 + lr)] =
                fmaxf(acc[mt][nt][e] + bb, 0.0f);
        }
    }

    // ---------------- K (split; transposed out only) ----------------------
    CONV_PASS(wkh, wkl, 1)
    {
      const int rbase = wv * 64 + lkq * 4;
#pragma unroll
      for (int mt = 0; mt < 4; ++mt)
#pragma unroll
        for (int e = 0; e < 4; ++e) {
          const int o = rbase + mt * 16 + e;
          const float bb = bk[o];
#pragma unroll
          for (int nt = 0; nt < 2; ++nt)
            acc[mt][nt][e] = fmaxf(acc[mt][nt][e] + bb, 0.0f);
        }
    }
    TRANSPOSE_OUT(outKT)   // clobbers xtlo (dead) via tbuf

    // ---------------- V (plain bf16, reads only xthi; transposed out) -----
    CONV_PASS(wvh, wvh, 0)
    {
      const int rbase = wv * 64 + lkq * 4;
#pragma unroll
      for (int mt = 0; mt < 4; ++mt)
#pragma unroll
        for (int e = 0; e < 4; ++e) {
          const int o = rbase + mt * 16 + e;
          const float bb = bv[o];
#pragma unroll
          for (int nt = 0; nt < 2; ++nt)
            acc[mt][nt][e] = fmaxf(acc[mt][nt][e] + bb, 0.0f);
        }
    }
    TRANSPOSE_OUT(outVT)
#undef CONV_PASS
#undef TRANSPOSE_OUT
  }
}

// ---------------------------------------------------------------------------
// K2: partial S = Q2 @ K2^T.  K read from x_Kw (outKT, [j][i2] layout),
// staged + split to bf16 hi/lo in LDS ([i2][jloc] layout, pre-transposed).
// 128 j-splits of 256 (2 stage tiles of 128).  512-thr blocks, 8 wave-tiles
// of 64x32.  Partials to Spart[b][split][128][128] (aliased with outb).
// ---------------------------------------------------------------------------
__global__ __launch_bounds__(512, 2) void k_qk(
    const float* __restrict__ Q2, const float* __restrict__ KT,
    float* __restrict__ Spart) {
  const int s = blockIdx.x, b = blockIdx.y;
  const int t = threadIdx.x;
  const int wvv = t >> 6, l = t & 63;
  const int wm = (wvv >> 2) * 64, wn = (wvv & 3) * 32;
  const int lr = l & 15, lkq = l >> 4, lk = lkq * 8;
  const size_t qb = (size_t)b * 4194304;
  const int jb = s * 256;

  __shared__ __align__(16) unsigned short khi[128][136];
  __shared__ __align__(16) unsigned short klo[128][136];

  const f4 fz = {0.f, 0.f, 0.f, 0.f};
  f4 acc[4][2];
#pragma unroll
  for (int mt = 0; mt < 4; ++mt)
#pragma unroll
    for (int nt = 0; nt < 2; ++nt) acc[mt][nt] = fz;

#pragma unroll 1
  for (int jt = 0; jt < 2; ++jt) {
    const int jsub = jb + jt * 128;
    __syncthreads();
    // stage KT[jsub..jsub+127][0..127] -> split-transposed LDS
#pragma unroll
    for (int it = 0; it < 8; ++it) {
      const int idx = it * 512 + t;
      const int jg = idx >> 5, i2c = (idx & 31) * 4;
      float4 v = *(const float4*)(KT + qb + (size_t)(jsub + jg) * 128 + i2c);
      const float* fv = (const float*)&v;
#pragma unroll
      for (int e = 0; e < 4; ++e) {
        union { float f; unsigned u; } w; w.f = fv[e];
        const unsigned short hi = (unsigned short)(w.u >> 16);
        union { unsigned u; float f; } hf; hf.u = (unsigned)hi << 16;
        khi[i2c + e][jg] = hi;
        klo[i2c + e][jg] = f2bf(w.f - hf.f);
      }
    }
    __syncthreads();

#pragma unroll 1
    for (int kk = 0; kk < 4; ++kk) {
      const int jloc = kk * 32 + lk;
      bf16x8 ahi[4], alo[4], bhi[2], blo[2];
#pragma unroll
      for (int mt = 0; mt < 4; ++mt) {
        const float* r = Q2 + qb + (size_t)(wm + mt * 16 + lr) * 32768 + jsub + jloc;
        split8t(*(const float4*)r, *(const float4*)(r + 4), ahi[mt], alo[mt]);
      }
#pragma unroll
      for (int nt = 0; nt < 2; ++nt) {
        bhi[nt] = *(const bf16x8*)&khi[wn + nt * 16 + lr][jloc];
        blo[nt] = *(const bf16x8*)&klo[wn + nt * 16 + lr][jloc];
      }
#pragma unroll
      for (int mt = 0; mt < 4; ++mt)
#pragma unroll
        for (int nt = 0; nt < 2; ++nt) {
          acc[mt][nt] = MFMA16(ahi[mt], bhi[nt], acc[mt][nt]);
          acc[mt][nt] = MFMA16(ahi[mt], blo[nt], acc[mt][nt]);
          acc[mt][nt] = MFMA16(alo[mt], bhi[nt], acc[mt][nt]);
        }
    }
  }

  float* out = Spart + ((size_t)(b * 128 + s)) * 16384;
#pragma unroll
  for (int mt = 0; mt < 4; ++mt)
#pragma unroll
    for (int e = 0; e < 4; ++e) {
      const int i1 = wm + mt * 16 + lkq * 4 + e;
#pragma unroll
      for (int nt = 0; nt < 2; ++nt)
        out[i1 * 128 + (wn + nt * 16 + lr)] = acc[mt][nt][e];
    }
}

// ---------------------------------------------------------------------------
// K2b: reduce the 128 partials -> S[b][128][128]
// ---------------------------------------------------------------------------
__global__ __launch_bounds__(256) void k_sred(
    const float* __restrict__ Spart, float* __restrict__ S) {
  const int e = blockIdx.x * 256 + threadIdx.x;  // 0..16383
  const int b = blockIdx.y;
  const float* p = Spart + (size_t)b * 128 * 16384 + e;
  float s0 = 0.f, s1 = 0.f, s2 = 0.f, s3 = 0.f;
#pragma unroll 4
  for (int s = 0; s < 128; s += 4) {
    s0 += p[(size_t)s * 16384];
    s1 += p[(size_t)(s + 1) * 16384];
    s2 += p[(size_t)(s + 2) * 16384];
    s3 += p[(size_t)(s + 3) * 16384];
  }
  S[b * 16384 + e] = (s0 + s1) + (s2 + s3);
}

// ---------------------------------------------------------------------------
// K3: softmax over axis i1 (per column i2).  32-lane shuffle reductions.
// ---------------------------------------------------------------------------
__global__ __launch_bounds__(256) void k_softmax(
    const float* __restrict__ S, const float* __restrict__ gin,
    float* __restrict__ attnO, float* __restrict__ gammaO,
    unsigned short* __restrict__ attnTg) {
  const int cb = blockIdx.x, b = blockIdx.y;
  const int t = threadIdx.x;
  const int col = cb * 8 + (t >> 5);
  const int r = t & 31;
  const float* Sb = S + b * 16384;
  float v[4];
#pragma unroll
  for (int j = 0; j < 4; ++j) v[j] = Sb[(r + 32 * j) * 128 + col];
  float m = fmaxf(fmaxf(v[0], v[1]), fmaxf(v[2], v[3]));
#pragma unroll
  for (int k = 16; k >= 1; k >>= 1) m = fmaxf(m, __shfl_xor(m, k, 32));
  float sum = 0.f;
#pragma unroll
  for (int j = 0; j < 4; ++j) { v[j] = expf(v[j] - m); sum += v[j]; }
#pragma unroll
  for (int k = 16; k >= 1; k >>= 1) sum += __shfl_xor(sum, k, 32);
  const float inv = 1.0f / sum;
  const float g = gin[0];
#pragma unroll
  for (int j = 0; j < 4; ++j) {
    const float p2 = v[j] * inv;
    attnO[b * 16384 + (r + 32 * j) * 128 + col] = p2;
    attnTg[(size_t)b * 16384 + (size_t)col * 128 + (r + 32 * j)] = f2bf(p2 * g);
  }
  if (b == 0 && cb == 0 && t == 0) gammaO[0] = gin[0];
}

// ---------------------------------------------------------------------------
// K4: out1 = V^T @ attn (gamma folded in attnTg), bf16 out to ws.
// ---------------------------------------------------------------------------
__global__ __launch_bounds__(256) void k_pv(
    const float* __restrict__ VT, const unsigned short* __restrict__ attnTg,
    unsigned short* __restrict__ outb) {
  const int jblk = blockIdx.x, b = blockIdx.y;
  const int t = threadIdx.x;
  const int wvv = t >> 6, l = t & 63;
  const int lr = l & 15, lkq = l >> 4, lk = lkq * 8;
  const size_t vb = (size_t)b * 4194304;
  const int j0 = jblk * 256 + wvv * 64;
  const f4 fz = {0.f, 0.f, 0.f, 0.f};
  f4 acc[4][8];
#pragma unroll
  for (int mt = 0; mt < 4; ++mt)
#pragma unroll
    for (int nt = 0; nt < 8; ++nt) acc[mt][nt] = fz;

#pragma unroll
  for (int kk = 0; kk < 4; ++kk) {
    const int k0 = kk * 32 + lk;
    bf16x8 av[4], bt[8];
#pragma unroll
    for (int mt = 0; mt < 4; ++mt) {
      const float* r = VT + vb + (size_t)(j0 + mt * 16 + lr) * 128 + k0;
      av[mt] = pack8t(*(const float4*)r, *(const float4*)(r + 4));
    }
#pragma unroll
    for (int nt = 0; nt < 8; ++nt)
      bt[nt] = *(const bf16x8*)(attnTg + (size_t)b * 16384 +
                                (size_t)(nt * 16 + lr) * 128 + k0);
#pragma unroll
    for (int mt = 0; mt < 4; ++mt)
#pragma unroll
      for (int nt = 0; nt < 8; ++nt)
        acc[mt][nt] = MFMA16(av[mt], bt[nt], acc[mt][nt]);
  }
#pragma unroll
  for (int mt = 0; mt < 4; ++mt)
#pragma unroll
    for (int e = 0; e < 4; ++e) {
      const int j = j0 + mt * 16 + lkq * 4 + e;
#pragma unroll
      for (int nt = 0; nt < 8; ++nt)
        outb[vb + (size_t)j * 128 + (nt * 16 + lr)] = f2bf(acc[mt][nt][e]);
    }
}

// ---------------------------------------------------------------------------
// K5: out_w = Wu @ out + bu.  Block: 256 ch x 128 pos (2 subtiles of 64).
// outw stores are nontemporal (never re-read; keep caches for hot data).
// ---------------------------------------------------------------------------
__global__ __launch_bounds__(256) void k_up(
    const unsigned short* __restrict__ outb, const unsigned short* __restrict__ wuh,
    const float* __restrict__ bu, float* __restrict__ outw) {
  const int pbv = blockIdx.x, b = blockIdx.y;
  const int t = threadIdx.x;
  __shared__ unsigned short ot[64][264];
  const int wv = t >> 6, l = t & 63;
  const int lr = l & 15, lkq = l >> 4, lk = lkq * 8;
  const f4 fz = {0.f, 0.f, 0.f, 0.f};
  const size_t ob2 = (size_t)b * 4194304;

#pragma unroll 1
  for (int st = 0; st < 2; ++st) {
    const int p0 = pbv * 128 + st * 64;
    __syncthreads();
    {
      const int cp = t & 127;
      const int ph = (t >> 7) * 32;
      const unsigned short* row0 = outb + ((size_t)b * 256 + 2 * cp) * 16384 + p0 + ph;
      const unsigned* r0 = (const unsigned*)row0;
      const unsigned* r1 = (const unsigned*)(row0 + 16384);
#pragma unroll
      for (int k = 0; k < 16; ++k) {
        const unsigned a0 = r0[k], a1 = r1[k];
        const int p = ph + 2 * k;
        *(unsigned*)&ot[p][2 * cp] = (a0 & 0xffffu) | (a1 << 16);
        *(unsigned*)&ot[p + 1][2 * cp] = (a0 >> 16) | (a1 & 0xffff0000u);
      }
    }
    __syncthreads();

    f4 acc[4][4];
#pragma unroll
    for (int mt = 0; mt < 4; ++mt)
#pragma unroll
      for (int nt = 0; nt < 4; ++nt) acc[mt][nt] = fz;

#pragma unroll 1
    for (int kk = 0; kk < 8; ++kk) {
      const int c0 = kk * 32 + lk;
      bf16x8 a[4], bt[4];
#pragma unroll
      for (int mt = 0; mt < 4; ++mt)
        a[mt] = *(const bf16x8*)(wuh + (wv * 64 + mt * 16 + lr) * 256 + c0);
#pragma unroll
      for (int nt = 0; nt < 4; ++nt)
        bt[nt] = *(const bf16x8*)&ot[nt * 16 + lr][c0];
#pragma unroll
      for (int mt = 0; mt < 4; ++mt)
#pragma unroll
        for (int nt = 0; nt < 4; ++nt)
          acc[mt][nt] = MFMA16(a[mt], bt[nt], acc[mt][nt]);
    }
    const int rbase = wv * 64 + lkq * 4;
#pragma unroll
    for (int mt = 0; mt < 4; ++mt)
#pragma unroll
      for (int e = 0; e < 4; ++e) {
        const int o = rbase + mt * 16 + e;
        const float bb = bu[o];
#pragma unroll
        for (int nt = 0; nt < 4; ++nt)
          __builtin_nontemporal_store(
              acc[mt][nt][e] + bb,
              &outw[ob2 + (size_t)o * 16384 + (p0 + nt * 16 + lr)]);
      }
  }
}

// ---------------------------------------------------------------------------
extern "C" void kernel_launch(void* const* d_in, const int* in_sizes, int n_in,
                              void* d_out, int out_size, void* d_ws, size_t ws_size,
                              hipStream_t stream) {
  (void)in_sizes; (void)n_in; (void)out_size; (void)ws_size;
  const float* x  = (const float*)d_in[0];
  const float* Wq = (const float*)d_in[1];
  const float* bq = (const float*)d_in[2];
  const float* Wk = (const float*)d_in[3];
  const float* bk = (const float*)d_in[4];
  const float* Wv = (const float*)d_in[5];
  const float* bv = (const float*)d_in[6];
  const float* Wu = (const float*)d_in[7];
  const float* bu = (const float*)d_in[8];
  const float* gm = (const float*)d_in[9];

  float* dout   = (float*)d_out;
  float* outw   = dout;                 // [4,256,128,128]
  float* outQ   = dout + 16777216;      // x_Qw  (contiguous conv out)
  float* outKT  = dout + 33554432;      // x_Kw  (transposed)
  float* outVT  = dout + 50331648;      // x_Vw  (transposed)
  float* gammaO = dout + 67108864;      // gamma
  float* attnO  = dout + 67108865;      // attn [4,128,128]

  // ws layout (Spart and outb ALIAS: disjoint lifetimes, stream-ordered)
  char* wsb = (char*)d_ws;
  float* Spart = (float*)(wsb);                             // 32 MiB (k_qk -> k_sred)
  unsigned short* outb = (unsigned short*)(wsb);            // 32 MiB (k_pv -> k_up)
  float* S     = (float*)(wsb + 33554432);                  // 256 KiB
  unsigned short* attnTg = (unsigned short*)(wsb + 33816576);  // 128 KiB
  unsigned short* wqh = (unsigned short*)(wsb + 33947648);
  unsigned short* wql = wqh + 65536;
  unsigned short* wkh = wql + 65536;
  unsigned short* wkl = wkh + 65536;
  unsigned short* wvh = wkl + 65536;
  unsigned short* wuh = wvh + 65536;

  k_prep<<<dim3(256), dim3(256), 0, stream>>>(Wq, Wk, Wv, Wu,
                                              wqh, wql, wkh, wkl, wvh, wuh);
  k_qkv<<<dim3(256, 4), dim3(256), 0, stream>>>(x, wqh, wql, wkh, wkl, wvh,
                                                bq, bk, bv,
                                                outQ, outKT, outVT);
  k_qk<<<dim3(128, 4), dim3(512), 0, stream>>>(outQ, outKT, Spart);
  k_sred<<<dim3(64, 4), dim3(256), 0, stream>>>(Spart, S);
  k_softmax<<<dim3(16, 4), dim3(256), 0, stream>>>(S, gm, attnO, gammaO, attnTg);
  k_pv<<<dim3(128, 4), dim3(256), 0, stream>>>(outVT, attnTg, outb);
  k_up<<<dim3(128, 4), dim3(256), 0, stream>>>(outb, wuh, bu, outw);
}